// Round 2
// baseline (151.364 us; speedup 1.0000x reference)
//
#include <hip/hip_runtime.h>
#include <math.h>

#define N_POINTS   262144
#define NUM_FREQS  10
#define NUM_VOXELS 512
#define CAP        2048    // slots per voxel bucket (mean 512, +68 sigma)

// R11: voxel-major restructure.
// R9/R10's block-local sort gave only ~1.6 pts/voxel of locality, so the
// weight gather stayed lane-divergent (~40-64 distinct lines per wave-load,
// ~100 MB of divergent L2 traffic) -- that, not barriers, was the ~20 us.
// Now: global bucket-by-voxel (atomic scatter into ws), then block-per-voxel
// compute where all lanes share ONE voxel's 384 B of fp16 weights ->
// broadcast loads, zero LDS, zero barriers, no unpermute.
//
// ws layout (need ~16.5 MB, have 256 MB):
//   [0,      196608)   Wp   fp16 512 x 3 x 64 (layout v2, pad col 3)
//   [196608, 198656)   cur  int[512] bucket counters (memsetAsync to 0)
//   [262144, +16 MB)   sorted float4[512*2048]  (x,y,z, bits(row_id))
//
// Dispatches: memsetAsync(cur) -> pack_scatter -> voxel_compute.

typedef _Float16 half2v __attribute__((ext_vector_type(2)));

__device__ __forceinline__ half2v u2h(unsigned int u) {
    union { unsigned int u; half2v h; } c; c.u = u; return c.h;
}

__device__ __forceinline__ float dot2acc(half2v a, half2v b, float acc) {
#if __has_builtin(__builtin_amdgcn_fdot2)
    return __builtin_amdgcn_fdot2(a, b, acc, false);
#else
    return acc + (float)a[0] * (float)b[0] + (float)a[1] * (float)b[1];
#endif
}

__device__ __forceinline__ half2v pkrtz(float a, float b) {
#if __has_builtin(__builtin_amdgcn_cvt_pkrtz)
    auto r = __builtin_amdgcn_cvt_pkrtz(a, b);   // v_cvt_pkrtz_f16_f32
    union { decltype(r) r_; half2v h; } c; c.r_ = r; return c.h;
#else
    half2v h; h[0] = (_Float16)a; h[1] = (_Float16)b; return h;
#endif
}

// posenc (double-angle recurrence; 2^f*x exact in fp32, recurrence err ~1e-4)
// packed to half2 via v_cvt_pkrtz, + dot against 3 fp16 rows of voxel v.
// In voxel_compute the voxel is block-uniform -> weight loads broadcast.
__device__ __forceinline__ void posenc_pack_dot(
    float x0, float x1, float x2, const _Float16* __restrict__ Wp, int v,
    float& a0, float& a1, float& a2)
{
    half2v eh[32];                       // 64 halfs = 32 VGPRs
    eh[0] = pkrtz(x0, x1);
    eh[1] = pkrtz(x2, 0.0f);             // pairs with zero pad col 3

    float s0, c0, s1, c1, s2, c2;
    __sincosf(x0, &s0, &c0);
    __sincosf(x1, &s1, &c1);
    __sincosf(x2, &s2, &c2);
    #pragma unroll
    for (int f = 0; f < NUM_FREQS; ++f) {
        const int b = 2 + 3 * f;         // pair index of [s0 s1 | s2 c0 | c1 c2]
        eh[b + 0] = pkrtz(s0, s1);
        eh[b + 1] = pkrtz(s2, c0);
        eh[b + 2] = pkrtz(c1, c2);
        if (f < NUM_FREQS - 1) {
            const float ns0 = 2.0f*s0*c0, nc0 = c0*c0 - s0*s0;
            const float ns1 = 2.0f*s1*c1, nc1 = c1*c1 - s1*s1;
            const float ns2 = 2.0f*s2*c2, nc2 = c2*c2 - s2*s2;
            s0 = ns0; c0 = nc0; s1 = ns1; c1 = nc1; s2 = ns2; c2 = nc2;
        }
    }

    const uint4* __restrict__ wb = (const uint4*)(Wp + (size_t)v * 192);
    float acc[3];
    #pragma unroll
    for (int r = 0; r < 3; ++r) {
        float a = 0.0f;
        #pragma unroll
        for (int k = 0; k < 8; ++k) {
            const uint4 q = wb[r * 8 + k];
            a = dot2acc(u2h(q.x), eh[4*k + 0], a);
            a = dot2acc(u2h(q.y), eh[4*k + 1], a);
            a = dot2acc(u2h(q.z), eh[4*k + 2], a);
            a = dot2acc(u2h(q.w), eh[4*k + 3], a);
        }
        acc[r] = a;
    }
    a0 = acc[0]; a1 = acc[1]; a2 = acc[2];
}

// ---------------------------------------------------------------------------
// K2: fused weight-pack + point scatter.  560 blocks x 512.
//   blocks [0,512):   scatter role -- bucket point i=(b*512+t) by voxel.
//   blocks [512,560): pack role -- fp32 W -> fp16 Wp (layout v2), 4 halfs/thr.
// ---------------------------------------------------------------------------
__global__ __launch_bounds__(512) void pack_scatter(
    const float* __restrict__ X, const float* __restrict__ W,
    const int* __restrict__ row_ids, const int* __restrict__ voxel_ids,
    _Float16* __restrict__ Wp, int* __restrict__ cur,
    float4* __restrict__ sorted)
{
    const int b = blockIdx.x;
    if (b >= 512) {
        const int gid = (b - 512) * 512 + threadIdx.x;    // [0, 24576)
        const int v   = gid / 48;                         // voxel
        const int e4  = gid % 48;                         // 4-half group
        const int row = e4 >> 4;                          // 0..2
        const int g   = e4 & 15;                          // group in row
        union { _Float16 h[4]; float2 f2; } u;
        #pragma unroll
        for (int j = 0; j < 4; ++j) {
            const int pc = 4 * g + j;                     // packed col 0..63
            float val = 0.0f;
            if (pc != 3) {
                const int wc = pc - (pc >= 4);            // W col 0..62
                val = W[v * 189 + row * 63 + wc];
            }
            u.h[j] = (_Float16)val;                       // RNE for weights
        }
        *reinterpret_cast<float2*>(Wp + (size_t)v * 192 + row * 64 + 4 * g) = u.f2;
        return;
    }

    const int i  = b * 512 + threadIdx.x;
    const int v  = voxel_ids[i];
    const float x0 = X[3*i + 0];
    const float x1 = X[3*i + 1];
    const float x2 = X[3*i + 2];
    const int r  = row_ids[i];
    const int pos = atomicAdd(&cur[v], 1);                // device-scope
    if (pos < CAP)
        sorted[(size_t)v * CAP + pos] =
            make_float4(x0, x1, x2, __int_as_float(r));
}

// ---------------------------------------------------------------------------
// K3: block-per-voxel compute.  512 blocks x 256, no LDS, no barriers.
// All lanes use the same voxel's weights -> broadcast (1-line) loads.
// ---------------------------------------------------------------------------
__global__ __launch_bounds__(256) void voxel_compute(
    const _Float16* __restrict__ Wp, const int* __restrict__ cur,
    const float4* __restrict__ sorted, float* __restrict__ out)
{
    const int v = blockIdx.x;
    int n = cur[v];
    if (n > CAP) n = CAP;
    const float4* __restrict__ sp = sorted + (size_t)v * CAP;

    for (int j = threadIdx.x; j < n; j += 256) {
        const float4 p = sp[j];                           // coalesced
        float a0, a1, a2;
        posenc_pack_dot(p.x, p.y, p.z, Wp, v, a0, a1, a2);
        const int r = __float_as_int(p.w);
        out[3*r + 0] = a0;
        out[3*r + 1] = a1;
        out[3*r + 2] = a2;
    }
}

// ---------------------------------------------------------------------------
// Fallback (R1 kernel) if ws too small for the bucket layout.
// ---------------------------------------------------------------------------
__global__ __launch_bounds__(256) void voxlin_fallback(
    const float* __restrict__ X, const float* __restrict__ W,
    const int* __restrict__ row_ids, const int* __restrict__ voxel_ids,
    float* __restrict__ out)
{
    const int i = blockIdx.x * 256 + threadIdx.x;
    if (i >= N_POINTS) return;
    const float x0 = X[3*i], x1 = X[3*i+1], x2 = X[3*i+2];
    const int v = voxel_ids[i];
    const float* __restrict__ w0 = W + v * 189;
    const float* __restrict__ w1 = w0 + 63;
    const float* __restrict__ w2 = w0 + 126;
    float a0 = x0*w0[0] + x1*w0[1] + x2*w0[2];
    float a1 = x0*w1[0] + x1*w1[1] + x2*w1[2];
    float a2 = x0*w2[0] + x1*w2[1] + x2*w2[2];
    float s0, c0, s1, c1, s2, c2;
    __sincosf(x0, &s0, &c0); __sincosf(x1, &s1, &c1); __sincosf(x2, &s2, &c2);
    #pragma unroll
    for (int f = 0; f < NUM_FREQS; ++f) {
        const int b = 3 + 6*f;
        a0 += s0*w0[b] + s1*w0[b+1] + s2*w0[b+2] + c0*w0[b+3] + c1*w0[b+4] + c2*w0[b+5];
        a1 += s0*w1[b] + s1*w1[b+1] + s2*w1[b+2] + c0*w1[b+3] + c1*w1[b+4] + c2*w1[b+5];
        a2 += s0*w2[b] + s1*w2[b+1] + s2*w2[b+2] + c0*w2[b+3] + c1*w2[b+4] + c2*w2[b+5];
        if (f < NUM_FREQS - 1) {
            const float ns0 = 2.0f*s0*c0, nc0 = c0*c0 - s0*s0;
            const float ns1 = 2.0f*s1*c1, nc1 = c1*c1 - s1*s1;
            const float ns2 = 2.0f*s2*c2, nc2 = c2*c2 - s2*s2;
            s0 = ns0; c0 = nc0; s1 = ns1; c1 = nc1; s2 = ns2; c2 = nc2;
        }
    }
    const int rr = row_ids[i];
    out[3*rr] = a0; out[3*rr+1] = a1; out[3*rr+2] = a2;
}

// ---------------------------------------------------------------------------
extern "C" void kernel_launch(void* const* d_in, const int* in_sizes, int n_in,
                              void* d_out, int out_size, void* d_ws, size_t ws_size,
                              hipStream_t stream) {
    const float* X         = (const float*)d_in[0];
    const float* W         = (const float*)d_in[1];
    const int*   row_ids   = (const int*)d_in[2];
    const int*   voxel_ids = (const int*)d_in[3];
    float*       out       = (float*)d_out;

    const size_t OFF_WP     = 0;
    const size_t OFF_CUR    = 196608;
    const size_t OFF_SORTED = 262144;
    const size_t need = OFF_SORTED + (size_t)NUM_VOXELS * CAP * sizeof(float4);

    if (ws_size >= need) {
        char* ws = (char*)d_ws;
        _Float16* Wp     = (_Float16*)(ws + OFF_WP);
        int*      cur    = (int*)     (ws + OFF_CUR);
        float4*   sorted = (float4*)  (ws + OFF_SORTED);

        hipMemsetAsync(cur, 0, NUM_VOXELS * sizeof(int), stream);
        pack_scatter<<<560, 512, 0, stream>>>(X, W, row_ids, voxel_ids,
                                              Wp, cur, sorted);
        voxel_compute<<<NUM_VOXELS, 256, 0, stream>>>(Wp, cur, sorted, out);
    } else {
        voxlin_fallback<<<(N_POINTS + 255) / 256, 256, 0, stream>>>(
            X, W, row_ids, voxel_ids, out);
    }
}

// Round 3
// 81.972 us; speedup vs baseline: 1.8465x; 1.8465x over previous
//
#include <hip/hip_runtime.h>
#include <math.h>

#define N_POINTS   262144
#define NUM_FREQS  10
#define NUM_VOXELS 512
#define HALF_VOX   256
#define VSTRIDE    200                        // halfs per voxel (400 B; 25 uint4)
#define W_FLOATS_PER_HALF (HALF_VOX * 189)    // 48384

// R12: single fused kernel, ZERO workspace, zero atomics, zero sort.
// Post-mortem R11: device-scope atomicAdd bucketing = 83 us at 0.14% VALUBusy
// (cross-XCD counter ping-pong).  Post-mortem R9/R10: per-lane-divergent
// weight gather from L2 (64 lines/wave-instr) was the real cost, not
// barriers.  Fix: stage HALF the fp16 weight table (256 voxels) in LDS at a
// 400 B padded stride (8 bank-rotation classes; unpadded 384 B stride would
// be 16-way conflict) and let lanes gather divergently from LDS, twice:
//   stage half0 -> bar -> compute lanes with v<256 -> bar ->
//   stage half1 -> bar -> compute lanes with v>=256 -> coalesced out
// posenc/sincos once per point; results live in registers; no unpermute.
// Weight layout per voxel: 3 rows x 64 halfs, pad col 3 (zero) so enc pairs
// are (x0,x1),(x2,0),(s0,s1),(s2,c0),(c1,c2)... matching v_cvt_pkrtz pairs.

typedef _Float16 half2v __attribute__((ext_vector_type(2)));

__device__ __forceinline__ half2v u2h(unsigned int u) {
    union { unsigned int u; half2v h; } c; c.u = u; return c.h;
}

__device__ __forceinline__ float dot2acc(half2v a, half2v b, float acc) {
#if __has_builtin(__builtin_amdgcn_fdot2)
    return __builtin_amdgcn_fdot2(a, b, acc, false);
#else
    return acc + (float)a[0] * (float)b[0] + (float)a[1] * (float)b[1];
#endif
}

__device__ __forceinline__ half2v pkrtz(float a, float b) {
#if __has_builtin(__builtin_amdgcn_cvt_pkrtz)
    auto r = __builtin_amdgcn_cvt_pkrtz(a, b);   // v_cvt_pkrtz_f16_f32
    union { decltype(r) r_; half2v h; } c; c.r_ = r; return c.h;
#else
    half2v h; h[0] = (_Float16)a; h[1] = (_Float16)b; return h;
#endif
}

// ---------------------------------------------------------------------------
// 256 blocks x 1024 threads, one point per thread.  LDS: 100 KB half-table.
// ---------------------------------------------------------------------------
__global__ __launch_bounds__(1024) void voxlin_lds(
    const float* __restrict__ X,
    const float* __restrict__ W,
    const int* __restrict__ row_ids,
    const int* __restrict__ voxel_ids,
    float* __restrict__ out)
{
    __shared__ _Float16 lw[HALF_VOX * VSTRIDE];   // 102400 B

    const int t = threadIdx.x;
    const int i = blockIdx.x * 1024 + t;

    const int   v  = voxel_ids[i];
    const float x0 = X[3*i + 0];
    const float x1 = X[3*i + 1];
    const float x2 = X[3*i + 2];
    const int   r  = row_ids[i];

    // ---- posenc once (double-angle recurrence), packed to half2 ----
    half2v eh[32];
    eh[0] = pkrtz(x0, x1);
    eh[1] = pkrtz(x2, 0.0f);                 // pairs with zero pad col 3
    {
        float s0, c0, s1, c1, s2, c2;
        __sincosf(x0, &s0, &c0);
        __sincosf(x1, &s1, &c1);
        __sincosf(x2, &s2, &c2);
        #pragma unroll
        for (int f = 0; f < NUM_FREQS; ++f) {
            const int b = 2 + 3 * f;         // [s0 s1 | s2 c0 | c1 c2]
            eh[b + 0] = pkrtz(s0, s1);
            eh[b + 1] = pkrtz(s2, c0);
            eh[b + 2] = pkrtz(c1, c2);
            if (f < NUM_FREQS - 1) {
                const float ns0 = 2.0f*s0*c0, nc0 = c0*c0 - s0*s0;
                const float ns1 = 2.0f*s1*c1, nc1 = c1*c1 - s1*s1;
                const float ns2 = 2.0f*s2*c2, nc2 = c2*c2 - s2*s2;
                s0 = ns0; c0 = nc0; s1 = ns1; c1 = nc1; s2 = ns2; c2 = nc2;
            }
        }
    }

    float a0 = 0.0f, a1 = 0.0f, a2 = 0.0f;

    #pragma unroll
    for (int h = 0; h < 2; ++h) {
        // ---- stage half h: W floats [h*48384, (h+1)*48384), coalesced ----
        const float* __restrict__ Wh = W + h * W_FLOATS_PER_HALF;
        for (int idx = t; idx < W_FLOATS_PER_HALF; idx += 1024) {
            const float wv  = Wh[idx];
            const int   lv  = idx / 189;               // local voxel 0..255
            const int   e   = idx - lv * 189;
            const int   row = e / 63;
            const int   col = e - row * 63;
            const int   pc  = col + (col >= 3);        // packed col, skip pad
            lw[lv * VSTRIDE + row * 64 + pc] = (_Float16)wv;
        }
        // zero pads: cols {3,67,131} + tail halfs 192..199 (11 per voxel)
        if (t < HALF_VOX * 11) {
            const int lv = t / 11, s = t - lv * 11;
            const int off = (s == 0) ? 3 : (s == 1) ? 67 : (s == 2) ? 131
                                                        : (189 + s); // 192..199
            lw[lv * VSTRIDE + off] = (_Float16)0.0f;
        }
        __syncthreads();

        // ---- masked compute: lanes whose voxel is in this half ----
        if ((v >> 8) == h) {
            const uint4* __restrict__ wb =
                (const uint4*)lw + (v & (HALF_VOX - 1)) * 25;  // 200 halfs = 25 uint4
            float acc[3];
            #pragma unroll
            for (int rr = 0; rr < 3; ++rr) {
                float a = 0.0f;
                #pragma unroll
                for (int k = 0; k < 8; ++k) {
                    const uint4 q = wb[rr * 8 + k];
                    a = dot2acc(u2h(q.x), eh[4*k + 0], a);
                    a = dot2acc(u2h(q.y), eh[4*k + 1], a);
                    a = dot2acc(u2h(q.z), eh[4*k + 2], a);
                    a = dot2acc(u2h(q.w), eh[4*k + 3], a);
                }
                acc[rr] = a;
            }
            a0 = acc[0]; a1 = acc[1]; a2 = acc[2];
        }
        __syncthreads();   // protect LDS before restage (no-op cost after h=1)
    }

    // ---- full-wave write-out in original row order ----
    out[3*r + 0] = a0;
    out[3*r + 1] = a1;
    out[3*r + 2] = a2;
}

// ---------------------------------------------------------------------------
extern "C" void kernel_launch(void* const* d_in, const int* in_sizes, int n_in,
                              void* d_out, int out_size, void* d_ws, size_t ws_size,
                              hipStream_t stream) {
    const float* X         = (const float*)d_in[0];
    const float* W         = (const float*)d_in[1];
    const int*   row_ids   = (const int*)d_in[2];
    const int*   voxel_ids = (const int*)d_in[3];
    float*       out       = (float*)d_out;
    (void)d_ws; (void)ws_size;   // workspace unused: no pack pass, no buckets

    voxlin_lds<<<N_POINTS / 1024, 1024, 0, stream>>>(X, W, row_ids, voxel_ids, out);
}

// Round 4
// 69.553 us; speedup vs baseline: 2.1762x; 1.1786x over previous
//
#include <hip/hip_runtime.h>
#include <math.h>

#define N_POINTS   262144
#define NUM_FREQS  10
#define NUM_VOXELS 512
#define HALF_VOX   256
#define VSTRIDE    200     // halfs per voxel (400 B = 100 dwords; bank-group
                           // rotation (25v+j) mod 8 = (v+j) mod 8 -> balanced)
#define HALF_HALFS (HALF_VOX * VSTRIDE)       // 51200 halfs = 100 KB
#define HALF_F4    (HALF_HALFS / 8)           // 6400 float4 per half-table

// R13: pre-packed LDS image + linear staging copy.
// Post-mortem R12 (82 us, kernel ~40): per-element repack in the staging loop
// (~18 VALU x 94 elems/thread, serialized at 1 block/CU barriers) was ~12 us;
// LDS gather adds ~6-10. Fix: one-shot pack_w writes the fp16 table to ws in
// the EXACT LDS image (stride 200, pads pre-zeroed), so per-block staging is
// a raw 100 KB float4 copy (6.25 ld+st per thread, zero math). Gather layout
// unchanged (voxel start bank-group = v mod 8, near-balanced for random v).
// Post-mortem R11 still stands: no global atomics anywhere.
//
// ws layout: [0, 204800) fp16 table, half h at h*102400 B:
//   half h, local voxel lv = v&255: 200 halfs = 3 rows x 64 (pad col 3 = 0)
//   + 8 zero tail halfs.  Gather reads uint4 j=0..23 (rows only).

typedef _Float16 half2v __attribute__((ext_vector_type(2)));

__device__ __forceinline__ half2v u2h(unsigned int u) {
    union { unsigned int u; half2v h; } c; c.u = u; return c.h;
}

__device__ __forceinline__ float dot2acc(half2v a, half2v b, float acc) {
#if __has_builtin(__builtin_amdgcn_fdot2)
    return __builtin_amdgcn_fdot2(a, b, acc, false);
#else
    return acc + (float)a[0] * (float)b[0] + (float)a[1] * (float)b[1];
#endif
}

__device__ __forceinline__ half2v pkrtz(float a, float b) {
#if __has_builtin(__builtin_amdgcn_cvt_pkrtz)
    auto r = __builtin_amdgcn_cvt_pkrtz(a, b);   // v_cvt_pkrtz_f16_f32
    union { decltype(r) r_; half2v h; } c; c.r_ = r; return c.h;
#else
    half2v h; h[0] = (_Float16)a; h[1] = (_Float16)b; return h;
#endif
}

// ---------------------------------------------------------------------------
// pack_w: fp32 W (1536x63) -> ws fp16 LDS image.  51200 groups of 4 halfs,
// one group per thread (float2 store).  50 blocks x 1024.
// ---------------------------------------------------------------------------
__global__ __launch_bounds__(1024) void pack_w(
    const float* __restrict__ W, _Float16* __restrict__ Wp)
{
    const int g  = blockIdx.x * 1024 + threadIdx.x;   // [0, 51200)
    const int v  = g / 50;                            // voxel 0..511
    const int p0 = (g - v * 50) * 4;                  // packed pos 0..196
    union { _Float16 h[4]; float2 f2; } u;
    #pragma unroll
    for (int j = 0; j < 4; ++j) {
        const int p = p0 + j;                         // 0..199
        float val = 0.0f;
        if (p < 192) {
            const int row = p >> 6, col = p & 63;
            if (col != 3) {
                const int wc = col - (col >= 4);      // W col 0..62
                val = W[v * 189 + row * 63 + wc];
            }
        }
        u.h[j] = (_Float16)val;                       // RNE for weights
    }
    _Float16* dst = Wp + (size_t)(v >> 8) * HALF_HALFS
                       + (size_t)(v & 255) * VSTRIDE + p0;
    *reinterpret_cast<float2*>(dst) = u.f2;           // 8B-aligned (p0 % 4 == 0)
}

// ---------------------------------------------------------------------------
// Main: 256 blocks x 1024 threads, one point per thread, 1 block/CU.
//   posenc once -> { linear-copy half-table to LDS; bar; masked gather+dot;
//   bar } x 2 -> coalesced out-writes.
// ---------------------------------------------------------------------------
__global__ __launch_bounds__(1024) void voxlin_lds(
    const float* __restrict__ X,
    const _Float16* __restrict__ Wp,
    const int* __restrict__ row_ids,
    const int* __restrict__ voxel_ids,
    float* __restrict__ out)
{
    __shared__ float4 lwv[HALF_F4];                   // 102400 B
    _Float16* const lw = (_Float16*)lwv;

    const int t = threadIdx.x;
    const int i = blockIdx.x * 1024 + t;

    const int   v  = voxel_ids[i];
    const float x0 = X[3*i + 0];
    const float x1 = X[3*i + 1];
    const float x2 = X[3*i + 2];
    const int   r  = row_ids[i];

    // ---- posenc once (double-angle recurrence), packed to half2 ----
    half2v eh[32];
    eh[0] = pkrtz(x0, x1);
    eh[1] = pkrtz(x2, 0.0f);                 // pairs with zero pad col 3
    {
        float s0, c0, s1, c1, s2, c2;
        __sincosf(x0, &s0, &c0);
        __sincosf(x1, &s1, &c1);
        __sincosf(x2, &s2, &c2);
        #pragma unroll
        for (int f = 0; f < NUM_FREQS; ++f) {
            const int b = 2 + 3 * f;         // [s0 s1 | s2 c0 | c1 c2]
            eh[b + 0] = pkrtz(s0, s1);
            eh[b + 1] = pkrtz(s2, c0);
            eh[b + 2] = pkrtz(c1, c2);
            if (f < NUM_FREQS - 1) {
                const float ns0 = 2.0f*s0*c0, nc0 = c0*c0 - s0*s0;
                const float ns1 = 2.0f*s1*c1, nc1 = c1*c1 - s1*s1;
                const float ns2 = 2.0f*s2*c2, nc2 = c2*c2 - s2*s2;
                s0 = ns0; c0 = nc0; s1 = ns1; c1 = nc1; s2 = ns2; c2 = nc2;
            }
        }
    }

    float a0 = 0.0f, a1 = 0.0f, a2 = 0.0f;

    #pragma unroll
    for (int h = 0; h < 2; ++h) {
        // ---- stage: raw linear copy of the pre-packed 100 KB image ----
        const float4* __restrict__ src = (const float4*)Wp + h * HALF_F4;
        #pragma unroll
        for (int j = t; j < HALF_F4; j += 1024)       // 6 or 7 iters
            lwv[j] = src[j];
        __syncthreads();

        // ---- masked compute: lanes whose voxel is in this half ----
        if ((v >> 8) == h) {
            const uint4* __restrict__ wb =
                (const uint4*)lw + (v & (HALF_VOX - 1)) * (VSTRIDE / 8);
            float acc[3];
            #pragma unroll
            for (int rr = 0; rr < 3; ++rr) {
                float a = 0.0f;
                #pragma unroll
                for (int k = 0; k < 8; ++k) {
                    const uint4 q = wb[rr * 8 + k];
                    a = dot2acc(u2h(q.x), eh[4*k + 0], a);
                    a = dot2acc(u2h(q.y), eh[4*k + 1], a);
                    a = dot2acc(u2h(q.z), eh[4*k + 2], a);
                    a = dot2acc(u2h(q.w), eh[4*k + 3], a);
                }
                acc[rr] = a;
            }
            a0 = acc[0]; a1 = acc[1]; a2 = acc[2];
        }
        __syncthreads();   // protect LDS before restage
    }

    // ---- full-wave write-out in original row order ----
    out[3*r + 0] = a0;
    out[3*r + 1] = a1;
    out[3*r + 2] = a2;
}

// ---------------------------------------------------------------------------
// Fallback (R1 kernel) if ws too small for the 400 KB packed image.
// ---------------------------------------------------------------------------
__global__ __launch_bounds__(256) void voxlin_fallback(
    const float* __restrict__ X, const float* __restrict__ W,
    const int* __restrict__ row_ids, const int* __restrict__ voxel_ids,
    float* __restrict__ out)
{
    const int i = blockIdx.x * 256 + threadIdx.x;
    if (i >= N_POINTS) return;
    const float x0 = X[3*i], x1 = X[3*i+1], x2 = X[3*i+2];
    const int v = voxel_ids[i];
    const float* __restrict__ w0 = W + v * 189;
    const float* __restrict__ w1 = w0 + 63;
    const float* __restrict__ w2 = w0 + 126;
    float a0 = x0*w0[0] + x1*w0[1] + x2*w0[2];
    float a1 = x0*w1[0] + x1*w1[1] + x2*w1[2];
    float a2 = x0*w2[0] + x1*w2[1] + x2*w2[2];
    float s0, c0, s1, c1, s2, c2;
    __sincosf(x0, &s0, &c0); __sincosf(x1, &s1, &c1); __sincosf(x2, &s2, &c2);
    #pragma unroll
    for (int f = 0; f < NUM_FREQS; ++f) {
        const int b = 3 + 6*f;
        a0 += s0*w0[b] + s1*w0[b+1] + s2*w0[b+2] + c0*w0[b+3] + c1*w0[b+4] + c2*w0[b+5];
        a1 += s0*w1[b] + s1*w1[b+1] + s2*w1[b+2] + c0*w1[b+3] + c1*w1[b+4] + c2*w1[b+5];
        a2 += s0*w2[b] + s1*w2[b+1] + s2*w2[b+2] + c0*w2[b+3] + c1*w2[b+4] + c2*w2[b+5];
        if (f < NUM_FREQS - 1) {
            const float ns0 = 2.0f*s0*c0, nc0 = c0*c0 - s0*s0;
            const float ns1 = 2.0f*s1*c1, nc1 = c1*c1 - s1*s1;
            const float ns2 = 2.0f*s2*c2, nc2 = c2*c2 - s2*s2;
            s0 = ns0; c0 = nc0; s1 = ns1; c1 = nc1; s2 = ns2; c2 = nc2;
        }
    }
    const int rr = row_ids[i];
    out[3*rr] = a0; out[3*rr+1] = a1; out[3*rr+2] = a2;
}

// ---------------------------------------------------------------------------
extern "C" void kernel_launch(void* const* d_in, const int* in_sizes, int n_in,
                              void* d_out, int out_size, void* d_ws, size_t ws_size,
                              hipStream_t stream) {
    const float* X         = (const float*)d_in[0];
    const float* W         = (const float*)d_in[1];
    const int*   row_ids   = (const int*)d_in[2];
    const int*   voxel_ids = (const int*)d_in[3];
    float*       out       = (float*)d_out;

    const size_t need = (size_t)2 * HALF_HALFS * sizeof(_Float16); // 400 KB

    if (ws_size >= need) {
        _Float16* Wp = (_Float16*)d_ws;
        pack_w<<<50, 1024, 0, stream>>>(W, Wp);
        voxlin_lds<<<N_POINTS / 1024, 1024, 0, stream>>>(X, Wp, row_ids,
                                                         voxel_ids, out);
    } else {
        voxlin_fallback<<<(N_POINTS + 255) / 256, 256, 0, stream>>>(
            X, W, row_ids, voxel_ids, out);
    }
}